// Round 4
// baseline (294.712 us; speedup 1.0000x reference)
//
#include <hip/hip_runtime.h>

#define RPB  128    // rows per block
#define NTHR 512    // 8 waves: wave = (rs 0..3, ch 0..1), 32 rows x 64 cols each

typedef _Float16 f16;
typedef _Float16 f16x2 __attribute__((ext_vector_type(2)));
typedef _Float16 f16x8 __attribute__((ext_vector_type(8)));
typedef float    f32x4 __attribute__((ext_vector_type(4)));

// ---- workspace layout: weights packed to f16 in B-fragment order ----
#define G_MW2 1024                 // 128*64/8
#define G_W   2048                 // 128*128/8
#define G_MW3 16384                // 1024*128/8
#define GO_MW2 0
#define GO_W2  (GO_MW2 + G_MW2)
#define GO_W3  (GO_W2 + G_W)
#define GO_W4  (GO_W3 + G_W)
#define GO_MW3 (GO_W4 + G_W)
#define G_TOT  (GO_MW3 + G_MW3)    // 23552 groups
#define WS_BYTES ((size_t)G_TOT * 16)

// ---- LDS overlay layout (bytes) ----
// region A: sH2 [128][136] f16                        34816
// region B: sY  [128][136] f16  ∪  { sMeta [128][16] f32 (8192) ; sH1 [128][72] f16 @+8192 (18432) }
// sStats [128][2] float2 ; sOut [128][2] f32 ; sX [128] f32
#define OFF_H2    0
#define OFF_B     34816
#define OFF_META  (OFF_B)
#define OFF_H1    (OFF_B + 8192)
#define OFF_STATS (OFF_B + 34816)      // 69632
#define OFF_OUT   (OFF_STATS + 2048)   // 71680
#define OFF_X     (OFF_OUT + 1024)     // 72704
#define SMEM_SZ   (OFF_X + 512)        // 73216 -> 2 blocks/CU

__device__ __forceinline__ f16x8 cvt8(const float* __restrict__ p) {
  const float4* p4 = (const float4*)p;
  float4 f0 = p4[0], f1 = p4[1];
  f16x8 o;
  o[0]=(f16)f0.x; o[1]=(f16)f0.y; o[2]=(f16)f0.z; o[3]=(f16)f0.w;
  o[4]=(f16)f1.x; o[5]=(f16)f1.y; o[6]=(f16)f1.z; o[7]=(f16)f1.w;
  return o;
}

__global__ void pack_weights(const float* __restrict__ mw2, const float* __restrict__ w2,
                             const float* __restrict__ w3,  const float* __restrict__ w4,
                             const float* __restrict__ mw3, f16x8* __restrict__ ws) {
  int g = blockIdx.x * blockDim.x + threadIdx.x;
  if (g >= G_TOT) return;
  if (g < GO_MW3) {                 // linear-packed matrices
    const float* W; int K; int local;
    if (g < GO_W2)       { W = mw2; K = 64;  local = g; }
    else if (g < GO_W3)  { W = w2;  K = 128; local = g - GO_W2; }
    else if (g < GO_W4)  { W = w3;  K = 128; local = g - GO_W3; }
    else                 { W = w4;  K = 128; local = g - GO_W4; }
    const int lane = local & 63, fb = local >> 6;
    const int ksteps = K >> 5;
    const int ks = fb % ksteps, n0g = fb / ksteps;
    const int n  = n0g * 16 + (lane & 15);
    const int k0 = ks * 32 + (lane >> 4) * 8;
    ws[g] = cvt8(W + (size_t)n * K + k0);
  } else {                          // mw3: AdaIN-interleaved
    const int local = g - GO_MW3;
    const int lane = local & 63, fb = local >> 6;   // fb: l(2) ch(1) tt(2) sb(1) ks(2)
    const int ks = fb & 3, sb = (fb >> 2) & 1, tt = (fb >> 3) & 3;
    const int ch = (fb >> 5) & 1, l = fb >> 6;
    const int n  = l * 256 + 2 * (ch * 64 + tt * 16 + (lane & 15)) + sb;
    const int k0 = ks * 32 + (lane >> 4) * 8;
    ws[g] = cvt8(mw3 + (size_t)n * 128 + k0);
  }
}

template<bool WS>
__device__ __forceinline__ f16x8 ldB(const f16x8* __restrict__ wp,
                                     const float* __restrict__ wf,
                                     int K, int n0, int ks, int lane) {
  if constexpr (WS) {
    return wp[((n0 >> 4) * (K >> 5) + ks) * 64 + lane];
  } else {
    const int n  = n0 + (lane & 15);
    const int k0 = ks * 32 + (lane >> 4) * 8;
    return cvt8(wf + (size_t)n * K + k0);
  }
}

template<bool WS>
__device__ __forceinline__ f16x8 ldB3(const f16x8* __restrict__ wp,
                                      const float* __restrict__ wf,
                                      int l, int ch, int tt, int sb, int ks, int lane) {
  if constexpr (WS) {
    const int fb = (((l * 2 + ch) * 4 + tt) * 2 + sb) * 4 + ks;
    return wp[fb * 64 + lane];
  } else {
    const int n  = l * 256 + 2 * (ch * 64 + tt * 16 + (lane & 15)) + sb;
    const int k0 = ks * 32 + (lane >> 4) * 8;
    return cvt8(wf + (size_t)n * 128 + k0);
  }
}

#define MFMA(a, b, c) __builtin_amdgcn_mfma_f32_16x16x32_f16((a), (b), (c), 0, 0, 0)

template<bool WS>
__global__ __launch_bounds__(NTHR, 4)
void adain_mfma(const float* __restrict__ x,   const float* __restrict__ meta,
                const float* __restrict__ mw1, const float* __restrict__ mb1,
                const float* __restrict__ mw2, const float* __restrict__ mb2,
                const float* __restrict__ mw3, const float* __restrict__ mb3,
                const float* __restrict__ w1,  const float* __restrict__ b1,
                const float* __restrict__ w2,  const float* __restrict__ b2,
                const float* __restrict__ w3,  const float* __restrict__ b3,
                const float* __restrict__ w4,  const float* __restrict__ b4,
                const float* __restrict__ w5,  const float* __restrict__ b5,
                const f16x8* __restrict__ wsp, float* __restrict__ out)
{
  __shared__ __align__(16) char smem[SMEM_SZ];
  f16    (*sH2)[136]   = (f16(*)[136])  (smem + OFF_H2);
  float  (*sMeta)[16]  = (float(*)[16]) (smem + OFF_META);
  f16    (*sH1)[72]    = (f16(*)[72])   (smem + OFF_H1);
  f16    (*sY)[136]    = (f16(*)[136])  (smem + OFF_B);
  float2 (*sStats)[2]  = (float2(*)[2]) (smem + OFF_STATS);
  float  (*sOut)[2]    = (float(*)[2])  (smem + OFF_OUT);
  float  *sX           = (float*)       (smem + OFF_X);

  const int t    = threadIdx.x;
  const int lane = t & 63;
  const int wid  = t >> 6;
  const int rs   = wid >> 1, ch = wid & 1;
  const int r0   = blockIdx.x * RPB;
  const int ln   = lane & 15;         // fragment n / A-row index
  const int bg   = lane >> 4;         // k-subgroup
  const int acol = bg * 8;
  const int g4   = bg * 4;            // D-row base offset

  // ---- stage metadata + x ----
  ((float4*)&sMeta[0][0])[t] = ((const float4*)(meta + (size_t)r0 * 16))[t];
  if (t < RPB) sX[t] = x[r0 + t];
  __syncthreads();

  // ---- h1 = relu(meta @ mw1.T + mb1) : (128,16)->(128,64), VALU ----
  {
    const int j = t & 63, rg = t >> 6;
    float wr[16];
    const float4* p4 = (const float4*)(mw1 + j * 16);
#pragma unroll
    for (int q = 0; q < 4; ++q) {
      float4 f = p4[q];
      wr[4*q] = f.x; wr[4*q+1] = f.y; wr[4*q+2] = f.z; wr[4*q+3] = f.w;
    }
    const float bj = mb1[j];
#pragma unroll
    for (int rr = 0; rr < 16; ++rr) {
      const int r = rg * 16 + rr;
      float acc = bj;
#pragma unroll
      for (int k = 0; k < 16; ++k) acc += wr[k] * sMeta[r][k];
      sH1[r][j] = (f16)fmaxf(acc, 0.0f);
    }
  }
  __syncthreads();

  // ---- h2 = relu(h1 @ mw2.T + mb2) : MFMA K=64, wave: 32 rows x 64 cols ----
  {
    f16x8 a0[2], a1[2];
#pragma unroll
    for (int p = 0; p < 2; ++p) {
      const int ar = rs * 32 + p * 16 + ln;
      a0[p] = *(const f16x8*)&sH1[ar][acol];
      a1[p] = *(const f16x8*)&sH1[ar][32 + acol];
    }
#pragma unroll
    for (int tt = 0; tt < 4; ++tt) {
      const int n0 = ch * 64 + tt * 16;
      f16x8 b0 = ldB<WS>(wsp + GO_MW2, mw2, 64, n0, 0, lane);
      f16x8 b1 = ldB<WS>(wsp + GO_MW2, mw2, 64, n0, 1, lane);
      const float bias = mb2[n0 + ln];
#pragma unroll
      for (int p = 0; p < 2; ++p) {
        f32x4 acc = {0.f, 0.f, 0.f, 0.f};
        acc = MFMA(a0[p], b0, acc);
        acc = MFMA(a1[p], b1, acc);
        const int dr = rs * 32 + p * 16 + g4;
#pragma unroll
        for (int q = 0; q < 4; ++q)
          sH2[dr + q][n0 + ln] = (f16)fmaxf(acc[q] + bias, 0.0f);
      }
    }
  }
  __syncthreads();

  // ---- 4 AdaIN layers, fully register-resident ----
#pragma unroll 1
  for (int l = 0; l < 4; ++l) {
    // (a) style: scale/bias land in matching lanes via interleaved packing
    f32x4 accS[2][4], accB[2][4];
    {
      f16x8 aH[2][4];
#pragma unroll
      for (int p = 0; p < 2; ++p) {
        const int ar = rs * 32 + p * 16 + ln;
#pragma unroll
        for (int ks = 0; ks < 4; ++ks)
          aH[p][ks] = *(const f16x8*)&sH2[ar][ks * 32 + acol];
      }
#pragma unroll
      for (int tt = 0; tt < 4; ++tt) {
#pragma unroll
        for (int sb = 0; sb < 2; ++sb) {
          f32x4 ac0 = {0.f,0.f,0.f,0.f}, ac1 = {0.f,0.f,0.f,0.f};
#pragma unroll
          for (int ks = 0; ks < 4; ++ks) {
            f16x8 b = ldB3<WS>(wsp + GO_MW3, mw3, l, ch, tt, sb, ks, lane);
            ac0 = MFMA(aH[0][ks], b, ac0);
            ac1 = MFMA(aH[1][ks], b, ac1);
          }
          if (sb == 0) { accS[0][tt] = ac0; accS[1][tt] = ac1; }
          else         { accB[0][tt] = ac0; accB[1][tt] = ac1; }
        }
      }
    }

    // (b) main-chain pre-activation in registers
    f32x4 accM[2][4];
    if (l == 0) {
#pragma unroll
      for (int tt = 0; tt < 4; ++tt) {
        const int c = ch * 64 + tt * 16 + ln;
        const float w1c = w1[c], b1c = b1[c];
#pragma unroll
        for (int p = 0; p < 2; ++p) {
          const int dr = rs * 32 + p * 16 + g4;
#pragma unroll
          for (int q = 0; q < 4; ++q) accM[p][tt][q] = sX[dr + q] * w1c + b1c;
        }
      }
    } else {
      const f16x8* Wp; const float* Wf; const float* Bv;
      if (l == 1)      { Wp = wsp + GO_W2; Wf = w2; Bv = b2; }
      else if (l == 2) { Wp = wsp + GO_W3; Wf = w3; Bv = b3; }
      else             { Wp = wsp + GO_W4; Wf = w4; Bv = b4; }
      f16x8 aY[2][4];
#pragma unroll
      for (int p = 0; p < 2; ++p) {
        const int ar = rs * 32 + p * 16 + ln;
#pragma unroll
        for (int ks = 0; ks < 4; ++ks)
          aY[p][ks] = *(const f16x8*)&sY[ar][ks * 32 + acol];
      }
#pragma unroll
      for (int tt = 0; tt < 4; ++tt) {
        const int n0 = ch * 64 + tt * 16;
        f32x4 ac0 = {0.f,0.f,0.f,0.f}, ac1 = {0.f,0.f,0.f,0.f};
#pragma unroll
        for (int ks = 0; ks < 4; ++ks) {
          f16x8 b = ldB<WS>(Wp, Wf, 128, n0, ks, lane);
          ac0 = MFMA(aY[0][ks], b, ac0);
          ac1 = MFMA(aY[1][ks], b, ac1);
        }
        const float bias = Bv[n0 + ln];
#pragma unroll
        for (int q = 0; q < 4; ++q) { ac0[q] += bias; ac1[q] += bias; }
        accM[0][tt] = ac0; accM[1][tt] = ac1;
      }
    }

    // (c) row stats: shuffle-reduce within 16-lane groups, cross-ch via LDS
#pragma unroll
    for (int p = 0; p < 2; ++p) {
      float s1[4] = {0,0,0,0}, s2[4] = {0,0,0,0};
#pragma unroll
      for (int tt = 0; tt < 4; ++tt)
#pragma unroll
        for (int q = 0; q < 4; ++q) {
          const float v = accM[p][tt][q];
          s1[q] += v; s2[q] += v * v;
        }
#pragma unroll
      for (int m = 1; m < 16; m <<= 1)
#pragma unroll
        for (int q = 0; q < 4; ++q) {
          s1[q] += __shfl_xor(s1[q], m, 64);
          s2[q] += __shfl_xor(s2[q], m, 64);
        }
      if (ln == 0) {
        const int dr = rs * 32 + p * 16 + g4;
#pragma unroll
        for (int q = 0; q < 4; ++q) sStats[dr + q][ch] = make_float2(s1[q], s2[q]);
      }
    }
    __syncthreads();

    float mu[2][4], rsg[2][4];
#pragma unroll
    for (int p = 0; p < 2; ++p) {
      const int dr = rs * 32 + p * 16 + g4;
#pragma unroll
      for (int q = 0; q < 4; ++q) {
        const float2 A = sStats[dr + q][0], Bc = sStats[dr + q][1];
        const float S1 = A.x + Bc.x, S2 = A.y + Bc.y;
        const float m = S1 * (1.0f / 128.0f);
        float var = (S2 - S1 * m) * (1.0f / 127.0f);
        var = fmaxf(var, 0.0f);
        mu[p][q]  = m;
        rsg[p][q] = 1.0f / (sqrtf(var) + 1e-6f);
      }
    }

    // (d) apply adain + lrelu; store sY (layers 0-2) or fuse w5 dot (layer 3)
    if (l < 3) {
#pragma unroll
      for (int tt = 0; tt < 4; ++tt) {
        const int c = ch * 64 + tt * 16 + ln;
        const float2 mb = *(const float2*)(mb3 + l * 256 + 2 * c);
#pragma unroll
        for (int p = 0; p < 2; ++p) {
          const int dr = rs * 32 + p * 16 + g4;
#pragma unroll
          for (int q = 0; q < 4; ++q) {
            const float sc = accS[p][tt][q] + mb.x;
            const float bi = accB[p][tt][q] + mb.y;
            float v = sc * (accM[p][tt][q] - mu[p][q]) * rsg[p][q] + bi;
            v = fmaxf(v, 0.01f * v);
            sY[dr + q][c] = (f16)v;
          }
        }
      }
      __syncthreads();
    } else {
      float o[2][4] = {{0,0,0,0},{0,0,0,0}};
#pragma unroll
      for (int tt = 0; tt < 4; ++tt) {
        const int c = ch * 64 + tt * 16 + ln;
        const float2 mb = *(const float2*)(mb3 + l * 256 + 2 * c);
        const float w5c = w5[c];
#pragma unroll
        for (int p = 0; p < 2; ++p)
#pragma unroll
          for (int q = 0; q < 4; ++q) {
            const float sc = accS[p][tt][q] + mb.x;
            const float bi = accB[p][tt][q] + mb.y;
            float v = sc * (accM[p][tt][q] - mu[p][q]) * rsg[p][q] + bi;
            v = fmaxf(v, 0.01f * v);
            o[p][q] += v * w5c;
          }
      }
#pragma unroll
      for (int m = 1; m < 16; m <<= 1)
#pragma unroll
        for (int p = 0; p < 2; ++p)
#pragma unroll
          for (int q = 0; q < 4; ++q) o[p][q] += __shfl_xor(o[p][q], m, 64);
      if (ln == 0) {
#pragma unroll
        for (int p = 0; p < 2; ++p) {
          const int dr = rs * 32 + p * 16 + g4;
#pragma unroll
          for (int q = 0; q < 4; ++q) sOut[dr + q][ch] = o[p][q];
        }
      }
      __syncthreads();
      if (t < RPB) {
        float v = sOut[t][0] + sOut[t][1] + b5[0];
        v = fmaxf(v, 0.01f * v);
        out[r0 + t] = v;
      }
    }
  }
}

extern "C" void kernel_launch(void* const* d_in, const int* in_sizes, int n_in,
                              void* d_out, int out_size, void* d_ws, size_t ws_size,
                              hipStream_t stream) {
  const float* x    = (const float*)d_in[0];
  const float* meta = (const float*)d_in[1];
  const float* mw1  = (const float*)d_in[2];
  const float* mb1  = (const float*)d_in[3];
  const float* mw2  = (const float*)d_in[4];
  const float* mb2  = (const float*)d_in[5];
  const float* mw3  = (const float*)d_in[6];
  const float* mb3  = (const float*)d_in[7];
  const float* w1   = (const float*)d_in[8];
  const float* b1   = (const float*)d_in[9];
  const float* w2   = (const float*)d_in[10];
  const float* b2   = (const float*)d_in[11];
  const float* w3   = (const float*)d_in[12];
  const float* b3   = (const float*)d_in[13];
  const float* w4   = (const float*)d_in[14];
  const float* b4   = (const float*)d_in[15];
  const float* w5   = (const float*)d_in[16];
  const float* b5   = (const float*)d_in[17];
  float* out = (float*)d_out;

  const int nrows = in_sizes[0];        // 262144
  const int grid  = nrows / RPB;        // 2048

  const bool usews = (ws_size >= WS_BYTES) && (d_ws != nullptr);
  if (usews) {
    f16x8* wsp = (f16x8*)d_ws;
    hipLaunchKernelGGL(pack_weights, dim3((G_TOT + 255) / 256), dim3(256), 0, stream,
                       mw2, w2, w3, w4, mw3, wsp);
    hipLaunchKernelGGL(adain_mfma<true>, dim3(grid), dim3(NTHR), 0, stream,
                       x, meta, mw1, mb1, mw2, mb2, mw3, mb3,
                       w1, b1, w2, b2, w3, b3, w4, b4, w5, b5, wsp, out);
  } else {
    hipLaunchKernelGGL(adain_mfma<false>, dim3(grid), dim3(NTHR), 0, stream,
                       x, meta, mw1, mb1, mw2, mb2, mw3, mb3,
                       w1, b1, w2, b2, w3, b3, w4, b4, w5, b5, (const f16x8*)nullptr, out);
  }
}

// Round 5
// 249.575 us; speedup vs baseline: 1.1809x; 1.1809x over previous
//
#include <hip/hip_runtime.h>

#define RPB  128    // rows per block
#define NTHR 512    // 8 waves: wave = (rs 0..3, ch 0..1), 32 rows x 64 cols each

typedef _Float16 f16;
typedef _Float16 f16x2 __attribute__((ext_vector_type(2)));
typedef _Float16 f16x8 __attribute__((ext_vector_type(8)));
typedef float    f32x4 __attribute__((ext_vector_type(4)));

// ---- workspace layout: weights packed to f16 in B-fragment order ----
#define G_MW2 1024                 // 128*64/8
#define G_W   2048                 // 128*128/8
#define G_MW3 16384                // 1024*128/8
#define GO_MW2 0
#define GO_W2  (GO_MW2 + G_MW2)
#define GO_W3  (GO_W2 + G_W)
#define GO_W4  (GO_W3 + G_W)
#define GO_MW3 (GO_W4 + G_W)
#define G_TOT  (GO_MW3 + G_MW3)    // 23552 groups
#define WS_BYTES ((size_t)G_TOT * 16)

// ---- LDS overlay layout (bytes) ----
// region A: sH2 [128][136] f16                        34816
// region B: sY  [128][136] f16  ∪  { sMeta [128][16] f32 ; sH1 [128][72] f16 }
// sStats [128][2] float2 ; sOut [128][2] f32 ; sX [128] f32
#define OFF_H2    0
#define OFF_B     34816
#define OFF_META  (OFF_B)
#define OFF_H1    (OFF_B + 8192)
#define OFF_STATS (OFF_B + 34816)      // 69632
#define OFF_OUT   (OFF_STATS + 2048)   // 71680
#define OFF_X     (OFF_OUT + 1024)     // 72704
#define SMEM_SZ   (OFF_X + 512)        // 73216 -> 2 blocks/CU by LDS

__device__ __forceinline__ f16x8 cvt8(const float* __restrict__ p) {
  const float4* p4 = (const float4*)p;
  float4 f0 = p4[0], f1 = p4[1];
  f16x8 o;
  o[0]=(f16)f0.x; o[1]=(f16)f0.y; o[2]=(f16)f0.z; o[3]=(f16)f0.w;
  o[4]=(f16)f1.x; o[5]=(f16)f1.y; o[6]=(f16)f1.z; o[7]=(f16)f1.w;
  return o;
}

__global__ void pack_weights(const float* __restrict__ mw2, const float* __restrict__ w2,
                             const float* __restrict__ w3,  const float* __restrict__ w4,
                             const float* __restrict__ mw3, f16x8* __restrict__ ws) {
  int g = blockIdx.x * blockDim.x + threadIdx.x;
  if (g >= G_TOT) return;
  if (g < GO_MW3) {                 // linear-packed matrices
    const float* W; int K; int local;
    if (g < GO_W2)       { W = mw2; K = 64;  local = g; }
    else if (g < GO_W3)  { W = w2;  K = 128; local = g - GO_W2; }
    else if (g < GO_W4)  { W = w3;  K = 128; local = g - GO_W3; }
    else                 { W = w4;  K = 128; local = g - GO_W4; }
    const int lane = local & 63, fb = local >> 6;
    const int ksteps = K >> 5;
    const int ks = fb % ksteps, n0g = fb / ksteps;
    const int n  = n0g * 16 + (lane & 15);
    const int k0 = ks * 32 + (lane >> 4) * 8;
    ws[g] = cvt8(W + (size_t)n * K + k0);
  } else {                          // mw3: AdaIN-interleaved
    const int local = g - GO_MW3;
    const int lane = local & 63, fb = local >> 6;   // fb: l(2) ch(1) tt(2) sb(1) ks(2)
    const int ks = fb & 3, sb = (fb >> 2) & 1, tt = (fb >> 3) & 3;
    const int ch = (fb >> 5) & 1, l = fb >> 6;
    const int n  = l * 256 + 2 * (ch * 64 + tt * 16 + (lane & 15)) + sb;
    const int k0 = ks * 32 + (lane >> 4) * 8;
    ws[g] = cvt8(mw3 + (size_t)n * 128 + k0);
  }
}

template<bool WS>
__device__ __forceinline__ f16x8 ldB(const f16x8* __restrict__ wp,
                                     const float* __restrict__ wf,
                                     int K, int n0, int ks, int lane) {
  if constexpr (WS) {
    return wp[((n0 >> 4) * (K >> 5) + ks) * 64 + lane];
  } else {
    const int n  = n0 + (lane & 15);
    const int k0 = ks * 32 + (lane >> 4) * 8;
    return cvt8(wf + (size_t)n * K + k0);
  }
}

template<bool WS>
__device__ __forceinline__ f16x8 ldB3(const f16x8* __restrict__ wp,
                                      const float* __restrict__ wf,
                                      int l, int ch, int tt, int sb, int ks, int lane) {
  if constexpr (WS) {
    const int fb = (((l * 2 + ch) * 4 + tt) * 2 + sb) * 4 + ks;
    return wp[fb * 64 + lane];
  } else {
    const int n  = l * 256 + 2 * (ch * 64 + tt * 16 + (lane & 15)) + sb;
    const int k0 = ks * 32 + (lane >> 4) * 8;
    return cvt8(wf + (size_t)n * 128 + k0);
  }
}

#define MFMA(a, b, c) __builtin_amdgcn_mfma_f32_16x16x32_f16((a), (b), (c), 0, 0, 0)

template<bool WS>
__global__ __launch_bounds__(NTHR, 2)   // bound 2: R3-proven 96-VGPR compile, no spill
void adain_mfma(const float* __restrict__ x,   const float* __restrict__ meta,
                const float* __restrict__ mw1, const float* __restrict__ mb1,
                const float* __restrict__ mw2, const float* __restrict__ mb2,
                const float* __restrict__ mw3, const float* __restrict__ mb3,
                const float* __restrict__ w1,  const float* __restrict__ b1,
                const float* __restrict__ w2,  const float* __restrict__ b2,
                const float* __restrict__ w3,  const float* __restrict__ b3,
                const float* __restrict__ w4,  const float* __restrict__ b4,
                const float* __restrict__ w5,  const float* __restrict__ b5,
                const f16x8* __restrict__ wsp, float* __restrict__ out)
{
  __shared__ __align__(16) char smem[SMEM_SZ];
  f16    (*sH2)[136]   = (f16(*)[136])  (smem + OFF_H2);
  float  (*sMeta)[16]  = (float(*)[16]) (smem + OFF_META);
  f16    (*sH1)[72]    = (f16(*)[72])   (smem + OFF_H1);
  f16    (*sY)[136]    = (f16(*)[136])  (smem + OFF_B);
  float2 (*sStats)[2]  = (float2(*)[2]) (smem + OFF_STATS);
  float  (*sOut)[2]    = (float(*)[2])  (smem + OFF_OUT);
  float  *sX           = (float*)       (smem + OFF_X);

  const int t    = threadIdx.x;
  const int lane = t & 63;
  const int wid  = t >> 6;
  const int rs   = wid >> 1, ch = wid & 1;
  const int r0   = blockIdx.x * RPB;
  const int ln   = lane & 15;         // fragment n / A-row index
  const int bg   = lane >> 4;         // k-subgroup
  const int acol = bg * 8;
  const int g4   = bg * 4;            // D-row base offset

  // ---- stage metadata + x ----
  ((float4*)&sMeta[0][0])[t] = ((const float4*)(meta + (size_t)r0 * 16))[t];
  if (t < RPB) sX[t] = x[r0 + t];
  __syncthreads();

  // ---- h1 = relu(meta @ mw1.T + mb1) : (128,16)->(128,64), VALU ----
  {
    const int j = t & 63, rg = t >> 6;
    float wr[16];
    const float4* p4 = (const float4*)(mw1 + j * 16);
#pragma unroll
    for (int q = 0; q < 4; ++q) {
      float4 f = p4[q];
      wr[4*q] = f.x; wr[4*q+1] = f.y; wr[4*q+2] = f.z; wr[4*q+3] = f.w;
    }
    const float bj = mb1[j];
#pragma unroll
    for (int rr = 0; rr < 16; ++rr) {
      const int r = rg * 16 + rr;
      float acc = bj;
#pragma unroll
      for (int k = 0; k < 16; ++k) acc += wr[k] * sMeta[r][k];
      sH1[r][j] = (f16)fmaxf(acc, 0.0f);
    }
  }
  __syncthreads();

  // ---- h2 = relu(h1 @ mw2.T + mb2) : MFMA K=64, wave: 32 rows x 64 cols ----
  {
    f16x8 a0[2], a1[2];
#pragma unroll
    for (int p = 0; p < 2; ++p) {
      const int ar = rs * 32 + p * 16 + ln;
      a0[p] = *(const f16x8*)&sH1[ar][acol];
      a1[p] = *(const f16x8*)&sH1[ar][32 + acol];
    }
#pragma unroll
    for (int tt = 0; tt < 4; ++tt) {
      const int n0 = ch * 64 + tt * 16;
      f16x8 b0 = ldB<WS>(wsp + GO_MW2, mw2, 64, n0, 0, lane);
      f16x8 b1 = ldB<WS>(wsp + GO_MW2, mw2, 64, n0, 1, lane);
      const float bias = mb2[n0 + ln];
#pragma unroll
      for (int p = 0; p < 2; ++p) {
        f32x4 acc = {0.f, 0.f, 0.f, 0.f};
        acc = MFMA(a0[p], b0, acc);
        acc = MFMA(a1[p], b1, acc);
        const int dr = rs * 32 + p * 16 + g4;
#pragma unroll
        for (int q = 0; q < 4; ++q)
          sH2[dr + q][n0 + ln] = (f16)fmaxf(acc[q] + bias, 0.0f);
      }
    }
  }
  __syncthreads();

  // ---- 4 AdaIN layers, fully register-resident ----
#pragma unroll 1
  for (int l = 0; l < 4; ++l) {
    // (a) style: scale/bias land in matching lanes via interleaved packing
    f32x4 accS[2][4], accB[2][4];
    {
      f16x8 aH[2][4];
#pragma unroll
      for (int p = 0; p < 2; ++p) {
        const int ar = rs * 32 + p * 16 + ln;
#pragma unroll
        for (int ks = 0; ks < 4; ++ks)
          aH[p][ks] = *(const f16x8*)&sH2[ar][ks * 32 + acol];
      }
#pragma unroll
      for (int tt = 0; tt < 4; ++tt) {
#pragma unroll
        for (int sb = 0; sb < 2; ++sb) {
          f32x4 ac0 = {0.f,0.f,0.f,0.f}, ac1 = {0.f,0.f,0.f,0.f};
#pragma unroll
          for (int ks = 0; ks < 4; ++ks) {
            f16x8 b = ldB3<WS>(wsp + GO_MW3, mw3, l, ch, tt, sb, ks, lane);
            ac0 = MFMA(aH[0][ks], b, ac0);
            ac1 = MFMA(aH[1][ks], b, ac1);
          }
          if (sb == 0) { accS[0][tt] = ac0; accS[1][tt] = ac1; }
          else         { accB[0][tt] = ac0; accB[1][tt] = ac1; }
        }
      }
    }

    // (b) main-chain pre-activation in registers
    f32x4 accM[2][4];
    if (l == 0) {
#pragma unroll
      for (int tt = 0; tt < 4; ++tt) {
        const int c = ch * 64 + tt * 16 + ln;
        const float w1c = w1[c], b1c = b1[c];
#pragma unroll
        for (int p = 0; p < 2; ++p) {
          const int dr = rs * 32 + p * 16 + g4;
#pragma unroll
          for (int q = 0; q < 4; ++q) accM[p][tt][q] = sX[dr + q] * w1c + b1c;
        }
      }
    } else {
      const f16x8* Wp; const float* Wf; const float* Bv;
      if (l == 1)      { Wp = wsp + GO_W2; Wf = w2; Bv = b2; }
      else if (l == 2) { Wp = wsp + GO_W3; Wf = w3; Bv = b3; }
      else             { Wp = wsp + GO_W4; Wf = w4; Bv = b4; }
      f16x8 aY[2][4];
#pragma unroll
      for (int p = 0; p < 2; ++p) {
        const int ar = rs * 32 + p * 16 + ln;
#pragma unroll
        for (int ks = 0; ks < 4; ++ks)
          aY[p][ks] = *(const f16x8*)&sY[ar][ks * 32 + acol];
      }
#pragma unroll
      for (int tt = 0; tt < 4; ++tt) {
        const int n0 = ch * 64 + tt * 16;
        f32x4 ac0 = {0.f,0.f,0.f,0.f}, ac1 = {0.f,0.f,0.f,0.f};
#pragma unroll
        for (int ks = 0; ks < 4; ++ks) {
          f16x8 b = ldB<WS>(Wp, Wf, 128, n0, ks, lane);
          ac0 = MFMA(aY[0][ks], b, ac0);
          ac1 = MFMA(aY[1][ks], b, ac1);
        }
        const float bias = Bv[n0 + ln];
#pragma unroll
        for (int q = 0; q < 4; ++q) { ac0[q] += bias; ac1[q] += bias; }
        accM[0][tt] = ac0; accM[1][tt] = ac1;
      }
    }

    // (c) row stats: shuffle-reduce within 16-lane groups, cross-ch via LDS
#pragma unroll
    for (int p = 0; p < 2; ++p) {
      float s1[4] = {0,0,0,0}, s2[4] = {0,0,0,0};
#pragma unroll
      for (int tt = 0; tt < 4; ++tt)
#pragma unroll
        for (int q = 0; q < 4; ++q) {
          const float v = accM[p][tt][q];
          s1[q] += v; s2[q] += v * v;
        }
#pragma unroll
      for (int m = 1; m < 16; m <<= 1)
#pragma unroll
        for (int q = 0; q < 4; ++q) {
          s1[q] += __shfl_xor(s1[q], m, 64);
          s2[q] += __shfl_xor(s2[q], m, 64);
        }
      if (ln == 0) {
        const int dr = rs * 32 + p * 16 + g4;
#pragma unroll
        for (int q = 0; q < 4; ++q) sStats[dr + q][ch] = make_float2(s1[q], s2[q]);
      }
    }
    __syncthreads();

    float mu[2][4], rsg[2][4];
#pragma unroll
    for (int p = 0; p < 2; ++p) {
      const int dr = rs * 32 + p * 16 + g4;
#pragma unroll
      for (int q = 0; q < 4; ++q) {
        const float2 A = sStats[dr + q][0], Bc = sStats[dr + q][1];
        const float S1 = A.x + Bc.x, S2 = A.y + Bc.y;
        const float m = S1 * (1.0f / 128.0f);
        float var = (S2 - S1 * m) * (1.0f / 127.0f);
        var = fmaxf(var, 0.0f);
        mu[p][q]  = m;
        rsg[p][q] = 1.0f / (sqrtf(var) + 1e-6f);
      }
    }

    // (d) apply adain + lrelu; store sY (layers 0-2) or fuse w5 dot (layer 3)
    if (l < 3) {
#pragma unroll
      for (int tt = 0; tt < 4; ++tt) {
        const int c = ch * 64 + tt * 16 + ln;
        const float2 mb = *(const float2*)(mb3 + l * 256 + 2 * c);
#pragma unroll
        for (int p = 0; p < 2; ++p) {
          const int dr = rs * 32 + p * 16 + g4;
#pragma unroll
          for (int q = 0; q < 4; ++q) {
            const float sc = accS[p][tt][q] + mb.x;
            const float bi = accB[p][tt][q] + mb.y;
            float v = sc * (accM[p][tt][q] - mu[p][q]) * rsg[p][q] + bi;
            v = fmaxf(v, 0.01f * v);
            sY[dr + q][c] = (f16)v;
          }
        }
      }
      __syncthreads();
    } else {
      float o[2][4] = {{0,0,0,0},{0,0,0,0}};
#pragma unroll
      for (int tt = 0; tt < 4; ++tt) {
        const int c = ch * 64 + tt * 16 + ln;
        const float2 mb = *(const float2*)(mb3 + l * 256 + 2 * c);
        const float w5c = w5[c];
#pragma unroll
        for (int p = 0; p < 2; ++p)
#pragma unroll
          for (int q = 0; q < 4; ++q) {
            const float sc = accS[p][tt][q] + mb.x;
            const float bi = accB[p][tt][q] + mb.y;
            float v = sc * (accM[p][tt][q] - mu[p][q]) * rsg[p][q] + bi;
            v = fmaxf(v, 0.01f * v);
            o[p][q] += v * w5c;
          }
      }
#pragma unroll
      for (int m = 1; m < 16; m <<= 1)
#pragma unroll
        for (int p = 0; p < 2; ++p)
#pragma unroll
          for (int q = 0; q < 4; ++q) o[p][q] += __shfl_xor(o[p][q], m, 64);
      if (ln == 0) {
#pragma unroll
        for (int p = 0; p < 2; ++p) {
          const int dr = rs * 32 + p * 16 + g4;
#pragma unroll
          for (int q = 0; q < 4; ++q) sOut[dr + q][ch] = o[p][q];
        }
      }
      __syncthreads();
      if (t < RPB) {
        float v = sOut[t][0] + sOut[t][1] + b5[0];
        v = fmaxf(v, 0.01f * v);
        out[r0 + t] = v;
      }
    }
  }
}

extern "C" void kernel_launch(void* const* d_in, const int* in_sizes, int n_in,
                              void* d_out, int out_size, void* d_ws, size_t ws_size,
                              hipStream_t stream) {
  const float* x    = (const float*)d_in[0];
  const float* meta = (const float*)d_in[1];
  const float* mw1  = (const float*)d_in[2];
  const float* mb1  = (const float*)d_in[3];
  const float* mw2  = (const float*)d_in[4];
  const float* mb2  = (const float*)d_in[5];
  const float* mw3  = (const float*)d_in[6];
  const float* mb3  = (const float*)d_in[7];
  const float* w1   = (const float*)d_in[8];
  const float* b1   = (const float*)d_in[9];
  const float* w2   = (const float*)d_in[10];
  const float* b2   = (const float*)d_in[11];
  const float* w3   = (const float*)d_in[12];
  const float* b3   = (const float*)d_in[13];
  const float* w4   = (const float*)d_in[14];
  const float* b4   = (const float*)d_in[15];
  const float* w5   = (const float*)d_in[16];
  const float* b5   = (const float*)d_in[17];
  float* out = (float*)d_out;

  const int nrows = in_sizes[0];        // 262144
  const int grid  = nrows / RPB;        // 2048

  const bool usews = (ws_size >= WS_BYTES) && (d_ws != nullptr);
  if (usews) {
    f16x8* wsp = (f16x8*)d_ws;
    hipLaunchKernelGGL(pack_weights, dim3((G_TOT + 255) / 256), dim3(256), 0, stream,
                       mw2, w2, w3, w4, mw3, wsp);
    hipLaunchKernelGGL(adain_mfma<true>, dim3(grid), dim3(NTHR), 0, stream,
                       x, meta, mw1, mb1, mw2, mb2, mw3, mb3,
                       w1, b1, w2, b2, w3, b3, w4, b4, w5, b5, wsp, out);
  } else {
    hipLaunchKernelGGL(adain_mfma<false>, dim3(grid), dim3(NTHR), 0, stream,
                       x, meta, mw1, mb1, mw2, mb2, mw3, mb3,
                       w1, b1, w2, b2, w3, b3, w4, b4, w5, b5, (const f16x8*)nullptr, out);
  }
}